// Round 7
// baseline (415.533 us; speedup 1.0000x reference)
//
#include <hip/hip_runtime.h>
#include <cstddef>
#include <cstdint>

#define LPIX 576
#define CCH  2048
#define NB   4
#define LROWS 2304   // NB*LPIX

typedef __attribute__((ext_vector_type(8))) short short8;
typedef __attribute__((ext_vector_type(4))) float f32x4;
typedef __attribute__((ext_vector_type(4))) unsigned short u16x4;

__device__ __forceinline__ unsigned short f2bf(float f) {
    uint32_t u = __builtin_bit_cast(uint32_t, f);
    u += 0x7fff + ((u >> 16) & 1);          // round-to-nearest-even
    return (unsigned short)(u >> 16);
}
__device__ __forceinline__ float bf2f(unsigned short s) {
    return __builtin_bit_cast(float, (uint32_t)s << 16);
}

__device__ __forceinline__ void gload_lds16(const void* g, void* l) {
    __builtin_amdgcn_global_load_lds((const __attribute__((address_space(1))) void*)g,
                                     (__attribute__((address_space(3))) void*)l, 16, 0, 0);
}

// ---------------- MFMA K-loop, BK=64 twin 32-k panels ----------------
template<int BM, int BN>
__device__ __forceinline__ void mm_core64(
    const short* __restrict__ Ab, int lda,
    const short* __restrict__ Bb, int ldb,
    int k0, int kend, short* As, short* Bs,
    int m0, int n0, f32x4 (&acc)[BM/32][BN/32])
{
    const int tid  = threadIdx.x;
    const int lane = tid & 63;
    const int w    = tid >> 6;
    const int wm = (w & 1) * (BM / 2);
    const int wn = (w >> 1) * (BN / 2);
    const int l15 = lane & 15;
    const int k8  = (lane >> 4) * 8;
    const int r   = tid >> 2;          // 0..63
    const int kk  = (tid & 3) * 8;     // 0,8,16,24 within a 32-k panel

    const short* Aptr[BM / 32]; short* Alds[BM / 32];
    #pragma unroll
    for (int u = 0; u < BM / 32; ++u) {
        const int p = u & 1, g = u >> 1;
        Aptr[u] = Ab + (size_t)(m0 + g * 64 + r) * lda + p * 32 + kk;
        Alds[u] = As + p * BM * 32 + g * 2048 + tid * 8;
    }
    const short* Bptr[BN / 32]; short* Blds[BN / 32];
    #pragma unroll
    for (int u = 0; u < BN / 32; ++u) {
        const int p = u & 1, g = u >> 1;
        Bptr[u] = Bb + (size_t)(n0 + g * 64 + r) * ldb + p * 32 + kk;
        Blds[u] = Bs + p * BN * 32 + g * 2048 + tid * 8;
    }

    for (int c0 = k0; c0 < kend; c0 += 64) {
        #pragma unroll
        for (int u = 0; u < BM / 32; ++u) gload_lds16(Aptr[u] + c0, Alds[u]);
        #pragma unroll
        for (int u = 0; u < BN / 32; ++u) gload_lds16(Bptr[u] + c0, Blds[u]);
        __syncthreads();
        #pragma unroll
        for (int s = 0; s < 2; ++s) {
            short8 fa[BM / 32], fb[BN / 32];
            #pragma unroll
            for (int i = 0; i < BM / 32; ++i)
                fa[i] = *(const short8*)(As + s * BM * 32 + (wm + i * 16 + l15) * 32 + k8);
            #pragma unroll
            for (int j = 0; j < BN / 32; ++j)
                fb[j] = *(const short8*)(Bs + s * BN * 32 + (wn + j * 16 + l15) * 32 + k8);
            #pragma unroll
            for (int i = 0; i < BM / 32; ++i)
                #pragma unroll
                for (int j = 0; j < BN / 32; ++j)
                    acc[i][j] = __builtin_amdgcn_mfma_f32_16x16x32_bf16(fa[i], fb[j], acc[i][j], 0, 0, 0);
        }
        __syncthreads();
    }
}

// ---------------- both conv weight casts in one dispatch ----------------
__global__ __launch_bounds__(256) void wcast2_k(const float* __restrict__ wq,
                                                const float* __restrict__ wk,
                                                short* __restrict__ Wb) {
    const float* W = blockIdx.y ? wk : wq;
    short* D = Wb + (size_t)blockIdx.y * CCH * CCH;
    int i = (blockIdx.x * 256 + threadIdx.x) * 4;
    float4 v = *(const float4*)(W + i);
    u16x4 u;
    u.x = f2bf(v.x); u.y = f2bf(v.y); u.z = f2bf(v.z); u.w = f2bf(v.w);
    *(u16x4*)(D + i) = u;
}

__global__ __launch_bounds__(256) void wcast_k(const float* __restrict__ W,
                                               short* __restrict__ Wb) {
    int i = (blockIdx.x * 256 + threadIdx.x) * 4;
    float4 v = *(const float4*)(W + i);
    u16x4 u;
    u.x = f2bf(v.x); u.y = f2bf(v.y); u.z = f2bf(v.z); u.w = f2bf(v.w);
    *(u16x4*)(Wb + i) = u;
}

// ---------------- merged transpose-cast: tgt & ref [b][c][l] fp32 -> T1[which][b][l][c] bf16 ----
__global__ __launch_bounds__(256) void tcast_k(const float* __restrict__ tgt,
                                               const float* __restrict__ ref,
                                               short* __restrict__ T1) {
    __shared__ float tile[32][33];
    const int z = blockIdx.z;
    const int b = z & 3, which = z >> 2;
    const float* X = (which ? ref : tgt) + (size_t)b * CCH * LPIX;
    const int c0 = blockIdx.y * 32;
    const int l0 = blockIdx.x * 32;
    const int tx = threadIdx.x, ty = threadIdx.y;
    #pragma unroll
    for (int j = 0; j < 4; ++j)
        tile[ty + j * 8][tx] = X[(size_t)(c0 + ty + j * 8) * LPIX + l0 + tx];
    __syncthreads();
    short* D = T1 + ((size_t)(which * NB + b) * LPIX) * CCH;
    #pragma unroll
    for (int j = 0; j < 4; ++j)
        D[(size_t)(l0 + ty + j * 8) * CCH + c0 + tx] = (short)f2bf(tile[tx][ty + j * 8]);
}

// ---------------- merged q/k conv: 128(row)x128(o) tiles over concatenated rows ----------
// 1D grid 576: xcd=id&7 owns 4 o-slabs (2 MB weights) + one T1 half, L2-resident
__global__ __launch_bounds__(256) void conv_k(
    const short* __restrict__ T1, const short* __restrict__ Wb,
    const float* __restrict__ bq, const float* __restrict__ bk,
    short* __restrict__ x2t, short* __restrict__ kt,
    float* __restrict__ nq, float* __restrict__ nk)
{
    __shared__ short As[128 * 64];
    __shared__ short Bs[128 * 64];
    const int id = blockIdx.x;
    const int xcd = id & 7, slot = id >> 3;          // slot 0..71
    const int sid = xcd * 4 + slot / 18;             // o-slab 0..31
    const int r18 = slot % 18;                       // rowtile within half
    const int which = sid >> 4;
    const int n0 = (sid & 15) * 128;                 // o
    const int m0 = r18 * 128;                        // row within half (0..2303)
    const short* Ab = T1 + (size_t)which * LROWS * CCH;
    const short* Bb = Wb + (size_t)which * CCH * CCH;
    const float* bias = which ? bk : bq;
    float* Nb = which ? nk : nq;
    f32x4 acc[4][4] = {};
    mm_core64<128, 128>(Ab, CCH, Bb, CCH, 0, CCH, As, Bs, m0, n0, acc);
    const int lane = threadIdx.x & 63, w = threadIdx.x >> 6;
    const int wm = (w & 1) * 64, wn = (w >> 1) * 64;
    const int l15 = lane & 15, quad = lane >> 4;
    float pv[4][4] = {};
    #pragma unroll
    for (int i = 0; i < 4; ++i)
        #pragma unroll
        for (int j = 0; j < 4; ++j) {
            const int gn = n0 + wn + j * 16 + l15;   // o
            const float bi = bias[gn];
            #pragma unroll
            for (int r = 0; r < 4; ++r) {
                const int gm = m0 + wm + i * 16 + quad * 4 + r;   // row
                float v = acc[i][j][r] + bi;
                pv[i][r] += v * v;
                if (which) kt[(size_t)gm * CCH + gn] = (short)f2bf(v);
                else       x2t[(size_t)gm * 4096 + gn] = (short)f2bf(v);
            }
        }
    #pragma unroll
    for (int i = 0; i < 4; ++i)
        #pragma unroll
        for (int r = 0; r < 4; ++r) {
            float s = pv[i][r];
            #pragma unroll
            for (int m = 1; m < 16; m <<= 1) s += __shfl_xor(s, m);
            if (l15 == 0) {
                const int gm = m0 + wm + i * 16 + quad * 4 + r;
                atomicAdd(&Nb[gm], s);
            }
        }
}

// ---------------- gram with split-K2: M_part[kc][b][lr][lt], 64x64 tiles ----------------
__global__ __launch_bounds__(256) void gram_k(
    const short* __restrict__ kt, const short* __restrict__ x2t,
    float* __restrict__ Mpart)
{
    __shared__ short As[64 * 64];
    __shared__ short Bs[64 * 64];
    const int z = blockIdx.z;
    const int b = z >> 1, kc = z & 1;
    const short* Ab = kt + (size_t)b * LPIX * CCH;
    const short* Bb = x2t + (size_t)b * LPIX * 4096;
    const int m0 = blockIdx.y * 64;   // lr
    const int n0 = blockIdx.x * 64;   // lt
    f32x4 acc[2][2] = {};
    mm_core64<64, 64>(Ab, CCH, Bb, 4096, kc * 1024, kc * 1024 + 1024, As, Bs, m0, n0, acc);
    float* Mb = Mpart + (size_t)(kc * NB + b) * LPIX * LPIX;
    const int lane = threadIdx.x & 63, w = threadIdx.x >> 6;
    const int wm = (w & 1) * 32, wn = (w >> 1) * 32;
    const int l15 = lane & 15, quad = lane >> 4;
    #pragma unroll
    for (int i = 0; i < 2; ++i)
        #pragma unroll
        for (int j = 0; j < 2; ++j) {
            const int gn = n0 + wn + j * 16 + l15;
            #pragma unroll
            for (int r = 0; r < 4; ++r) {
                const int gm = m0 + wm + i * 16 + quad * 4 + r;
                Mb[(size_t)gm * LPIX + gn] = acc[i][j][r];
            }
        }
}

// ---------------- out pre-init: out = bt[o]*S + PT ----------------
__global__ __launch_bounds__(256) void initout_k(
    const float* __restrict__ bt, const float* __restrict__ S,
    const float* __restrict__ PT, float* __restrict__ out)
{
    const int idx = blockIdx.x * 256 + threadIdx.x;          // over NB*CCH*144
    const int l4 = idx % 144;
    const int o  = (idx / 144) % CCH;
    const int b  = idx / (144 * CCH);
    const float bi = bt[o];
    float4 sv = *(const float4*)(S + b * LPIX + l4 * 4);
    float4 pv = *(const float4*)(PT + ((size_t)b * CCH + o) * LPIX + l4 * 4);
    float4 ov;
    ov.x = bi * sv.x + pv.x; ov.y = bi * sv.y + pv.y;
    ov.z = bi * sv.z + pv.z; ov.w = bi * sv.w + pv.w;
    *(float4*)(out + ((size_t)b * CCH + o) * LPIX + l4 * 4) = ov;
}

// ---------------- final: 128(o) x 128(row) split-K2, atomic accumulate into out ----------
// 1D grid 576 = 16 o x 18 row x 2 kc; xcd owns 2 o-tiles (2 MB weights L2-resident)
__global__ __launch_bounds__(256) void fin_k(
    const short* __restrict__ wtb, const short* __restrict__ x2t,
    const float* __restrict__ S, float* __restrict__ out)
{
    __shared__ short As[128 * 64];
    __shared__ short Bs[128 * 64];
    const int id = blockIdx.x;
    const int xcd = id & 7, slot = id >> 3;          // slot 0..71
    const int sid = xcd * 2 + slot / 36;             // o-tile 0..15
    const int rem = slot % 36;
    const int kc = rem / 18;
    const int m0 = sid * 128;                        // o
    const int n0 = (rem % 18) * 128;                 // row = b*576+l
    f32x4 acc[4][4] = {};
    mm_core64<128, 128>(wtb, 4096, x2t, 4096, kc * 2048, kc * 2048 + 2048, As, Bs, m0, n0, acc);
    const int lane = threadIdx.x & 63, w = threadIdx.x >> 6;
    const int wm = (w & 1) * 64, wn = (w >> 1) * 64;
    const int l15 = lane & 15, quad = lane >> 4;
    #pragma unroll
    for (int i = 0; i < 4; ++i)
        #pragma unroll
        for (int j = 0; j < 4; ++j) {
            const int gn = n0 + wn + j * 16 + l15;   // row
            const int b = gn / LPIX, l = gn - b * LPIX;
            const float sv = S[gn];
            #pragma unroll
            for (int r = 0; r < 4; ++r) {
                const int gm = m0 + wm + i * 16 + quad * 4 + r;   // o
                atomicAdd(&out[((size_t)b * CCH + gm) * LPIX + l], acc[i][j][r] * sv);
            }
        }
}

// ---------------- stage 1: fused 3x3-box invNk + 9-tap aggregation + chunk argmax ----
__global__ __launch_bounds__(256) void argmax1_k(
    const float* __restrict__ Mpart, const float* __restrict__ nk,
    float* __restrict__ Pv, int* __restrict__ Pi)
{
    const int b   = blockIdx.z;
    const int lrb = blockIdx.y;                 // ir row 0..23
    const int tx = threadIdx.x, ty = threadIdx.y;
    const int tid = ty * 64 + tx;
    __shared__ float invNkS[24];
    if (tid < 24) {
        const int jr = tid;
        float s = 0.f;
        #pragma unroll
        for (int di = -1; di <= 1; ++di) {
            const int ii = lrb + di;
            if ((unsigned)ii > 23u) continue;
            #pragma unroll
            for (int dj = -1; dj <= 1; ++dj) {
                const int jj = jr + dj;
                if ((unsigned)jj > 23u) continue;
                s += nk[b * LPIX + ii * 24 + jj];
            }
        }
        invNkS[jr] = 1.0f / fmaxf(sqrtf(s), 1e-12f);
    }
    __syncthreads();
    const int lt = blockIdx.x * 64 + tx;
    const int it = lt / 24, jt = lt % 24;
    const float* Mb0 = Mpart + (size_t)b * LPIX * LPIX;
    const float* Mb1 = Mpart + (size_t)(NB + b) * LPIX * LPIX;
    float best = -1e30f; int bidx = 0;
    #pragma unroll
    for (int i = 0; i < 6; ++i) {
        const int jr = ty + i * 4;
        const int lr = lrb * 24 + jr;
        const int base = lr * LPIX + lt;
        float g = 0.f;
        #pragma unroll
        for (int di = -1; di <= 1; ++di) {
            if ((unsigned)(lrb + di) > 23u || (unsigned)(it + di) > 23u) continue;
            #pragma unroll
            for (int dj = -1; dj <= 1; ++dj) {
                if ((unsigned)(jr + dj) > 23u || (unsigned)(jt + dj) > 23u) continue;
                const int o = base + (di * 24 + dj) * (LPIX + 1);
                g += Mb0[o] + Mb1[o];
            }
        }
        float v = g * invNkS[jr];
        if (v > best) { best = v; bidx = lr; }
    }
    __shared__ float rv[4][64];
    __shared__ int   ri[4][64];
    rv[ty][tx] = best; ri[ty][tx] = bidx;
    __syncthreads();
    if (ty == 0) {
        #pragma unroll
        for (int y = 1; y < 4; ++y) {
            float v = rv[y][tx]; int id = ri[y][tx];
            if (v > best || (v == best && id < bidx)) { best = v; bidx = id; }
        }
        Pv[((size_t)b * 24 + lrb) * LPIX + lt] = best;
        Pi[((size_t)b * 24 + lrb) * LPIX + lt] = bidx;
    }
}

// ---------------- stage 2: fold 24 partials, fused invNq ----------------
__global__ __launch_bounds__(256) void argmax2_k(
    const float* __restrict__ Pv, const int* __restrict__ Pi,
    const float* __restrict__ nq,
    float* __restrict__ S, int* __restrict__ Arg)
{
    int idx = blockIdx.x * 256 + threadIdx.x;
    if (idx >= NB * LPIX) return;
    int b = idx / LPIX, lt = idx % LPIX;
    int it = lt / 24, jt = lt % 24;
    float s = 0.f;
    #pragma unroll
    for (int di = -1; di <= 1; ++di) {
        const int ii = it + di;
        if ((unsigned)ii > 23u) continue;
        #pragma unroll
        for (int dj = -1; dj <= 1; ++dj) {
            const int jj = jt + dj;
            if ((unsigned)jj > 23u) continue;
            s += nq[b * LPIX + ii * 24 + jj];
        }
    }
    const float invNq = 1.0f / fmaxf(sqrtf(s), 1e-12f);
    float best = -1e30f; int bidx = 0;
    #pragma unroll
    for (int c = 0; c < 24; ++c) {
        float v = Pv[((size_t)b * 24 + c) * LPIX + lt];
        int  id = Pi[((size_t)b * 24 + c) * LPIX + lt];
        if (v > best || (v == best && id < bidx)) { best = v; bidx = id; }
    }
    S[idx]   = best * invNq;
    Arg[idx] = bidx;
}

// ---------------- gather best ref patches + fold (/9), XCD-swizzled ----------------
__global__ __launch_bounds__(256) void gather_k(
    const short* __restrict__ kt, const int* __restrict__ Arg,
    short* __restrict__ x2t)
{
    const int id = blockIdx.x;
    const int xcd = id & 7, slot = id >> 3;          // slot 0..71
    const int b  = xcd >> 1;
    const int l0 = ((xcd & 1) * 72 + slot) * 4;
    const int lane = threadIdx.x, ty = threadIdx.y;
    const int tid = ty * 64 + lane;
    __shared__ int tap[4][9];
    if (tid < 36) {
        int px = tid / 9, t9 = tid % 9;
        int l = l0 + px;
        int i = l / 24, j = l % 24;
        int ki = t9 / 3, kj = t9 % 3;
        int ip = i + 1 - ki, jp = j + 1 - kj;
        int off = -1;
        if (ip >= 0 && ip < 24 && jp >= 0 && jp < 24) {
            int a = Arg[b * LPIX + ip * 24 + jp];
            int rr = a / 24 + ki - 1;
            int cc = a % 24 + kj - 1;
            if (rr >= 0 && rr < 24 && cc >= 0 && cc < 24) off = rr * 24 + cc;
        }
        tap[px][t9] = off;
    }
    __syncthreads();
    const int l = l0 + ty;
    const short* Kb = kt + (size_t)b * LPIX * CCH;
    short* dst = x2t + ((size_t)b * LPIX + l) * 4096 + CCH;
    int t[9];
    #pragma unroll
    for (int i = 0; i < 9; ++i) t[i] = tap[ty][i];
    const float inv9 = 1.0f / 9.0f;
    #pragma unroll
    for (int j = 0; j < 8; ++j) {
        int c = (lane + j * 64) * 4;
        float s0 = 0.f, s1 = 0.f, s2 = 0.f, s3 = 0.f;
        #pragma unroll
        for (int t9 = 0; t9 < 9; ++t9) {
            int off = t[t9];
            if (off < 0) continue;
            u16x4 u = *(const u16x4*)(Kb + (size_t)off * CCH + c);
            s0 += bf2f(u.x); s1 += bf2f(u.y); s2 += bf2f(u.z); s3 += bf2f(u.w);
        }
        u16x4 o;
        o.x = f2bf(s0 * inv9); o.y = f2bf(s1 * inv9);
        o.z = f2bf(s2 * inv9); o.w = f2bf(s3 * inv9);
        *(u16x4*)(dst + c) = o;
    }
}

extern "C" void kernel_launch(void* const* d_in, const int* in_sizes, int n_in,
                              void* d_out, int out_size, void* d_ws, size_t ws_size,
                              hipStream_t stream) {
    const float* part_ref = (const float*)d_in[0];
    const float* part_tgt = (const float*)d_in[1];
    const float* wq = (const float*)d_in[2];
    const float* bq = (const float*)d_in[3];
    const float* wk = (const float*)d_in[4];
    const float* bk = (const float*)d_in[5];
    const float* wt = (const float*)d_in[6];
    const float* bt = (const float*)d_in[7];
    float* out = (float*)d_out;

    short* wqb2 = (short*)d_ws;
    short* wtb  = wqb2;                                       // reuse after convs
    short* T1   = wqb2 + (size_t)2 * CCH * CCH;
    short* kt   = T1 + (size_t)2 * LROWS * CCH;
    short* x2t  = kt + (size_t)LROWS * CCH;
    float* Mpart = (float*)T1;                                // aliases T1 (dead by gram time)
    float* nk    = (float*)(x2t + (size_t)LROWS * 4096);
    float* nq    = nk + LROWS;
    float* Sbuf  = nq + LROWS;
    int*   Arg   = (int*)(Sbuf + LROWS);
    float* Pv    = (float*)(Arg + LROWS);                     // 24*LROWS
    int*   Pi    = (int*)(Pv + (size_t)24 * LROWS);

    hipMemsetAsync(nk, 0, 2 * LROWS * sizeof(float), stream);  // nk|nq contiguous

    wcast2_k<<<dim3(4096, 2), 256, 0, stream>>>(wq, wk, wqb2);
    tcast_k<<<dim3(18, 64, 8), dim3(32, 8), 0, stream>>>(part_tgt, part_ref, T1);

    // q -> x2t[:, 0:2048]; k -> kt; fused channel-norm atomics (576 blocks, 128x128, swizzled)
    conv_k<<<576, 256, 0, stream>>>(T1, wqb2, bq, bk, x2t, kt, nq, nk);

    // gram split-K2 -> Mpart (648 blocks)
    gram_k<<<dim3(9, 9, 8), 256, 0, stream>>>(kt, x2t, Mpart);

    argmax1_k<<<dim3(9, 24, NB), dim3(64, 4), 0, stream>>>(Mpart, nk, Pv, Pi);
    argmax2_k<<<9, 256, 0, stream>>>(Pv, Pi, nq, Sbuf, Arg);

    // out = bt*S + PT  (fin accumulates on top atomically)
    initout_k<<<4608, 256, 0, stream>>>(bt, Sbuf, part_tgt, out);

    gather_k<<<576, dim3(64, 4), 0, stream>>>(kt, Arg, x2t);

    wcast_k<<<8192, 256, 0, stream>>>(wt, wtb);
    // final conv, 128x128 split-K2 (576 blocks, swizzled), atomic += acc*S
    fin_k<<<576, 256, 0, stream>>>(wtb, x2t, Sbuf, out);
}